// Round 4
// baseline (191.683 us; speedup 1.0000x reference)
//
#include <hip/hip_runtime.h>
#include <hip/hip_bf16.h>

// out = x @ (W + 16*(M@N))^T + b  where M(1024x8), N(8x1024) are folded TT cores.
// Pipeline: build Weff(bf16) [fold+update fused] -> cast x to bf16 ->
// m97-style bf16 MFMA GEMM with XOR-swizzled LDS k-chunks (kills 8-way bank
// conflicts without padding, which global_load_lds forbids).

#define D_DIM 1024
#define BS_ROWS 16384
#define ALPHA_F 16.0f
#define BM 128
#define BN 128
#define BK 32

using bf16   = __bf16;
using bf16x8 = __attribute__((ext_vector_type(8))) __bf16;
using bf16x4 = __attribute__((ext_vector_type(4))) __bf16;
using f32x4  = __attribute__((ext_vector_type(4))) float;

#define GPTR(p) (const __attribute__((address_space(1))) void*)(p)
#define SPTR(p) (__attribute__((address_space(3))) void*)(p)

// ---- Kernel A: Weff[o][d] = bf16( W[o][d] + 16 * (M@N)[d][o] ) --------------
// One block per output row o. M[1024][8] folded in LDS (redundant per block,
// ~130K FLOP — trivial); N[:,o] (8 floats) in registers.
__global__ __launch_bounds__(256) void build_weff_fused_kernel(
    const float* __restrict__ W,
    const float* __restrict__ c0, const float* __restrict__ c1,
    const float* __restrict__ c2, const float* __restrict__ c3,
    const float* __restrict__ c4, const float* __restrict__ c5,
    bf16* __restrict__ Weff)
{
    __shared__ float t2[1024];    // [i2*8+i1][p2] : 128 rows x 8  (i2 in [0,16))
    __shared__ float Msh[8192];   // [d][p3]
    const int tid = threadIdx.x;
    const int o = blockIdx.x;

    // Phase 1: t2[(i2*8+i1)][p2] = sum_p1 c0[0,i1,p1]*c1[p1,i2,p2]
    for (int e = tid; e < 1024; e += 256) {
        int p2 = e & 7, i2i1 = e >> 3;
        int i1 = i2i1 & 7, i2 = i2i1 >> 3;
        float s = 0.f;
        for (int p1 = 0; p1 < 8; ++p1)
            s += c0[i1 * 8 + p1] * c1[p1 * 128 + i2 * 8 + p2];
        t2[e] = s;
    }
    __syncthreads();
    // Phase 2: M[d][p3] = sum_p2 t2[i2*8+i1][p2]*c2[p2,i3,p3], d=i3*128+i2*8+i1
    for (int e = tid; e < 8192; e += 256) {
        int p3 = e & 7, d = e >> 3;
        int i1 = d & 7, i2 = (d >> 3) & 15, i3 = d >> 7;
        float s = 0.f;
        for (int p2 = 0; p2 < 8; ++p2)
            s += t2[(i2 * 8 + i1) * 8 + p2] * c2[p2 * 64 + i3 * 8 + p3];
        Msh[e] = s;
    }

    // N column for this o (each thread computes all 8 — tiny)
    int n1 = o >> 7, nn = o & 127, n2 = nn >> 3, n3 = nn & 7;
    float v[8];  // v[p4] = sum_p5 c4[p4,n2,p5]*c5[p5,n3,0]
    for (int p4 = 0; p4 < 8; ++p4) {
        float s = 0.f;
        for (int p5 = 0; p5 < 8; ++p5)
            s += c4[p4 * 128 + n2 * 8 + p5] * c5[p5 * 8 + n3];
        v[p4] = s;
    }
    float ncol[8];  // ncol[r3] = N[r3][o]
    for (int r3 = 0; r3 < 8; ++r3) {
        float s = 0.f;
        for (int p4 = 0; p4 < 8; ++p4)
            s += c3[r3 * 64 + n1 * 8 + p4] * v[p4];
        ncol[r3] = s;
    }
    __syncthreads();

    // Update: 4 consecutive d per thread
    int d0 = tid * 4;
    f32x4 w = *(const f32x4*)&W[o * D_DIM + d0];
    bf16x4 res;
    for (int k = 0; k < 4; ++k) {
        float acc = 0.f;
        for (int r = 0; r < 8; ++r)
            acc += Msh[(d0 + k) * 8 + r] * ncol[r];
        res[k] = (bf16)(w[k] + ALPHA_F * acc);
    }
    *(bf16x4*)&Weff[o * D_DIM + d0] = res;
}

// ---- Kernel B: cast x (fp32) -> xb (bf16), streaming ------------------------
__global__ void cast_x_kernel(const float* __restrict__ X, bf16* __restrict__ Xb)
{
    int i = (blockIdx.x * 256 + threadIdx.x) * 8;
    f32x4 a = *(const f32x4*)&X[i];
    f32x4 b = *(const f32x4*)&X[i + 4];
    bf16x8 v;
    v[0] = (bf16)a[0]; v[1] = (bf16)a[1]; v[2] = (bf16)a[2]; v[3] = (bf16)a[3];
    v[4] = (bf16)b[0]; v[5] = (bf16)b[1]; v[6] = (bf16)b[2]; v[7] = (bf16)b[3];
    *(bf16x8*)&Xb[i] = v;
}

// ---- Kernel C: 16384x1024x1024 bf16 MFMA GEMM + bias ------------------------
// XOR-swizzled LDS: chunk c of row r holds global k-chunk c ^ ((r>>1)&3).
// Staging lane loads global chunk (lane&3)^((lane>>3)&3); fragment for logical
// chunk `quad` of row (..+l15) reads LDS chunk quad^((l15>>1)&3).
// Bank math: 16 lanes/quad-group now hit 16*(r&1)+4*c+{0..3} covering all 32
// banks 2-way (free) instead of 8 banks 8-way (2.94x).
__global__ __launch_bounds__(256) void gemm_bb_kernel(
    const bf16* __restrict__ Xb,
    const bf16* __restrict__ Weff,
    const float* __restrict__ bias,
    float* __restrict__ Out)
{
    __shared__ __align__(16) bf16 As[BM][BK];  // 8 KB
    __shared__ __align__(16) bf16 Bs[BN][BK];  // 8 KB

    const int tid  = threadIdx.x;
    const int wave = tid >> 6, lane = tid & 63;
    const int mtile = blockIdx.x, ntile = blockIdx.y;
    const int wr = wave >> 1, wc = wave & 1;
    const int l15 = lane & 15, quad = lane >> 4;

    // Staging: wave w, issue j -> LDS bytes [(w*2+j)*1024, +1024)
    // rows (w*2+j)*16 + lane/4; global k-chunk swizzled by row bits 1-2.
    const int srow = wave * 32 + (lane >> 2);
    const int skof = (((lane & 3) ^ ((lane >> 3) & 3)) * 8);
    const bf16* asrc0 = Xb  + (size_t)(mtile * BM + srow) * D_DIM + skof;
    const bf16* asrc1 = asrc0 + 16 * D_DIM;
    const bf16* bsrc0 = Weff + (size_t)(ntile * BN + srow) * D_DIM + skof;
    const bf16* bsrc1 = bsrc0 + 16 * D_DIM;
    char* abase = (char*)&As[0][0];
    char* bbase = (char*)&Bs[0][0];
    void* adst0 = abase + wave * 2048;
    void* adst1 = abase + wave * 2048 + 1024;
    void* bdst0 = bbase + wave * 2048;
    void* bdst1 = bbase + wave * 2048 + 1024;

    // Fragment LDS chunk (elements): quad ^ ((l15>>1)&3), times 8 elems
    const int fchunk = (quad ^ ((l15 >> 1) & 3)) * 8;

    f32x4 acc[4][4];
    for (int i = 0; i < 4; ++i)
        for (int j = 0; j < 4; ++j)
            for (int r = 0; r < 4; ++r) acc[i][j][r] = 0.f;

    for (int kt = 0; kt < D_DIM / BK; ++kt) {
        const int ko = kt * BK;
        __builtin_amdgcn_global_load_lds(GPTR(asrc0 + ko), SPTR(adst0), 16, 0, 0);
        __builtin_amdgcn_global_load_lds(GPTR(asrc1 + ko), SPTR(adst1), 16, 0, 0);
        __builtin_amdgcn_global_load_lds(GPTR(bsrc0 + ko), SPTR(bdst0), 16, 0, 0);
        __builtin_amdgcn_global_load_lds(GPTR(bsrc1 + ko), SPTR(bdst1), 16, 0, 0);

        __syncthreads();

        bf16x8 af[4], bfr[4];
        for (int i = 0; i < 4; ++i)
            af[i] = *(const bf16x8*)&As[wr * 64 + i * 16 + l15][fchunk];
        for (int j = 0; j < 4; ++j)
            bfr[j] = *(const bf16x8*)&Bs[wc * 64 + j * 16 + l15][fchunk];
        for (int i = 0; i < 4; ++i)
            for (int j = 0; j < 4; ++j)
                acc[i][j] = __builtin_amdgcn_mfma_f32_16x16x32_bf16(
                    af[i], bfr[j], acc[i][j], 0, 0, 0);

        __syncthreads();
    }

    // Epilogue: C/D layout col = lane&15, row = quad*4 + reg
    float bj[4];
    for (int j = 0; j < 4; ++j)
        bj[j] = bias[ntile * BN + wc * 64 + j * 16 + l15];
    for (int i = 0; i < 4; ++i) {
        int row0 = mtile * BM + wr * 64 + i * 16 + quad * 4;
        for (int r = 0; r < 4; ++r) {
            float* orow = Out + (size_t)(row0 + r) * D_DIM + ntile * BN + wc * 64 + l15;
            for (int j = 0; j < 4; ++j)
                orow[j * 16] = acc[i][j][r] + bj[j];
        }
    }
}

// ---- Fallback GEMM (fp32 A staged via VALU convert) — used if ws too small --
__global__ __launch_bounds__(256) void gemm_bias_kernel(
    const float* __restrict__ X,
    const bf16* __restrict__ Weff,
    const float* __restrict__ bias,
    float* __restrict__ Out)
{
    __shared__ __align__(16) bf16 As[BM][BK];
    __shared__ __align__(16) bf16 Bs[BN][BK];

    const int tid  = threadIdx.x;
    const int wave = tid >> 6, lane = tid & 63;
    const int mtile = blockIdx.x, ntile = blockIdx.y;
    const int wr = wave >> 1, wc = wave & 1;
    const int l15 = lane & 15, quad = lane >> 4;

    const int ar = tid >> 1, ah = tid & 1;
    const float* xsrc = X + (size_t)(mtile * BM + ar) * D_DIM + ah * 16;
    bf16* adst = &As[ar][ah * 16];

    const bf16* bsrc0 = Weff + (size_t)(ntile * BN + wave * 32 + (lane >> 2)) * D_DIM
                        + (lane & 3) * 8;
    const bf16* bsrc1 = bsrc0 + 16 * D_DIM;
    char* bbase = (char*)&Bs[0][0];
    void* bdst0 = bbase + wave * 2048;
    void* bdst1 = bbase + wave * 2048 + 1024;

    f32x4 acc[4][4];
    for (int i = 0; i < 4; ++i)
        for (int j = 0; j < 4; ++j)
            for (int r = 0; r < 4; ++r) acc[i][j][r] = 0.f;

    for (int kt = 0; kt < D_DIM / BK; ++kt) {
        __builtin_amdgcn_global_load_lds(GPTR(bsrc0 + kt * BK), SPTR(bdst0), 16, 0, 0);
        __builtin_amdgcn_global_load_lds(GPTR(bsrc1 + kt * BK), SPTR(bdst1), 16, 0, 0);

        const f32x4* xp = (const f32x4*)(xsrc + kt * BK);
        f32x4 f0 = xp[0], f1 = xp[1], f2 = xp[2], f3 = xp[3];
        bf16x8 p0, p1;
        p0[0] = (bf16)f0[0]; p0[1] = (bf16)f0[1]; p0[2] = (bf16)f0[2]; p0[3] = (bf16)f0[3];
        p0[4] = (bf16)f1[0]; p0[5] = (bf16)f1[1]; p0[6] = (bf16)f1[2]; p0[7] = (bf16)f1[3];
        p1[0] = (bf16)f2[0]; p1[1] = (bf16)f2[1]; p1[2] = (bf16)f2[2]; p1[3] = (bf16)f2[3];
        p1[4] = (bf16)f3[0]; p1[5] = (bf16)f3[1]; p1[6] = (bf16)f3[2]; p1[7] = (bf16)f3[3];
        *(bf16x8*)adst = p0;
        *(bf16x8*)(adst + 8) = p1;

        __syncthreads();

        bf16x8 af[4], bfr[4];
        for (int i = 0; i < 4; ++i)
            af[i] = *(const bf16x8*)&As[wr * 64 + i * 16 + l15][quad * 8];
        for (int j = 0; j < 4; ++j)
            bfr[j] = *(const bf16x8*)&Bs[wc * 64 + j * 16 + l15][quad * 8];
        for (int i = 0; i < 4; ++i)
            for (int j = 0; j < 4; ++j)
                acc[i][j] = __builtin_amdgcn_mfma_f32_16x16x32_bf16(
                    af[i], bfr[j], acc[i][j], 0, 0, 0);

        __syncthreads();
    }

    float bj[4];
    for (int j = 0; j < 4; ++j)
        bj[j] = bias[ntile * BN + wc * 64 + j * 16 + l15];
    for (int i = 0; i < 4; ++i) {
        int row0 = mtile * BM + wr * 64 + i * 16 + quad * 4;
        for (int r = 0; r < 4; ++r) {
            float* orow = Out + (size_t)(row0 + r) * D_DIM + ntile * BN + wc * 64 + l15;
            for (int j = 0; j < 4; ++j)
                orow[j * 16] = acc[i][j][r] + bj[j];
        }
    }
}

extern "C" void kernel_launch(void* const* d_in, const int* in_sizes, int n_in,
                              void* d_out, int out_size, void* d_ws, size_t ws_size,
                              hipStream_t stream) {
    const float* x  = (const float*)d_in[0];
    const float* W  = (const float*)d_in[1];
    const float* b  = (const float*)d_in[2];
    const float* c0 = (const float*)d_in[3];
    const float* c1 = (const float*)d_in[4];
    const float* c2 = (const float*)d_in[5];
    const float* c3 = (const float*)d_in[6];
    const float* c4 = (const float*)d_in[7];
    const float* c5 = (const float*)d_in[8];
    float* out = (float*)d_out;

    // Workspace: Weff bf16 2MB @0 | Xb 32MB @4MB
    char* ws = (char*)d_ws;
    bf16* Weff = (bf16*)ws;
    bf16* Xb   = (bf16*)(ws + 4u * 1024u * 1024u);
    const size_t need = 4u * 1024u * 1024u + (size_t)BS_ROWS * D_DIM * 2u;

    build_weff_fused_kernel<<<D_DIM, 256, 0, stream>>>(W, c0, c1, c2, c3, c4, c5, Weff);

    dim3 grid(BS_ROWS / BM, D_DIM / BN);
    if (ws_size >= need) {
        cast_x_kernel<<<(BS_ROWS * D_DIM) / (256 * 8), 256, 0, stream>>>(x, Xb);
        gemm_bb_kernel<<<grid, 256, 0, stream>>>(Xb, Weff, b, out);
    } else {
        gemm_bias_kernel<<<grid, 256, 0, stream>>>(x, Weff, b, out);
    }
}

// Round 5
// 182.202 us; speedup vs baseline: 1.0520x; 1.0520x over previous
//
#include <hip/hip_runtime.h>
#include <hip/hip_bf16.h>

// out = x @ (W + 16*(M@N))^T + b  where M(1024x8), N(8x1024) are folded TT cores.
// Pipeline: prep (build Weff bf16 + cast x->bf16, one launch) ->
// bf16 MFMA GEMM, BK=64 (32 MFMA/barrier), XOR-swizzled LDS (conflict-free).

#define D_DIM 1024
#define BS_ROWS 16384
#define ALPHA_F 16.0f
#define BM 128
#define BN 128

using bf16   = __bf16;
using bf16x8 = __attribute__((ext_vector_type(8))) __bf16;
using bf16x4 = __attribute__((ext_vector_type(4))) __bf16;
using f32x4  = __attribute__((ext_vector_type(4))) float;

#define GPTR(p) (const __attribute__((address_space(1))) void*)(p)
#define SPTR(p) (__attribute__((address_space(3))) void*)(p)

// ---- Kernel A: fused prep.
// Blocks [0,1024): Weff[o][d] = bf16(W[o][d] + 16*(M@N)[d][o]), o = blockIdx.
// Blocks [1024,9216): cast x chunk to bf16.
__global__ __launch_bounds__(256) void prep_kernel(
    const float* __restrict__ X,
    const float* __restrict__ W,
    const float* __restrict__ c0, const float* __restrict__ c1,
    const float* __restrict__ c2, const float* __restrict__ c3,
    const float* __restrict__ c4, const float* __restrict__ c5,
    bf16* __restrict__ Weff, bf16* __restrict__ Xb)
{
    __shared__ float t2[1024];    // [i2*8+i1][p2] : 128 x 8  (i2 in [0,16))
    __shared__ float Msh[8192];   // [d][p3]
    const int tid = threadIdx.x;

    if (blockIdx.x >= 1024) {
        // cast: 2048 elements per block, 8 per thread
        size_t i = ((size_t)(blockIdx.x - 1024) * 256 + tid) * 8;
        f32x4 a = *(const f32x4*)&X[i];
        f32x4 b = *(const f32x4*)&X[i + 4];
        bf16x8 v;
        v[0] = (bf16)a[0]; v[1] = (bf16)a[1]; v[2] = (bf16)a[2]; v[3] = (bf16)a[3];
        v[4] = (bf16)b[0]; v[5] = (bf16)b[1]; v[6] = (bf16)b[2]; v[7] = (bf16)b[3];
        *(bf16x8*)&Xb[i] = v;
        return;
    }

    const int o = blockIdx.x;
    // Phase 1: t2[(i2*8+i1)][p2] = sum_p1 c0[0,i1,p1]*c1[p1,i2,p2]
    for (int e = tid; e < 1024; e += 256) {
        int p2 = e & 7, i2i1 = e >> 3;
        int i1 = i2i1 & 7, i2 = i2i1 >> 3;
        float s = 0.f;
        for (int p1 = 0; p1 < 8; ++p1)
            s += c0[i1 * 8 + p1] * c1[p1 * 128 + i2 * 8 + p2];
        t2[e] = s;
    }
    __syncthreads();
    // Phase 2: M[d][p3] = sum_p2 t2[i2*8+i1][p2]*c2[p2,i3,p3], d=i3*128+i2*8+i1
    for (int e = tid; e < 8192; e += 256) {
        int p3 = e & 7, d = e >> 3;
        int i1 = d & 7, i2 = (d >> 3) & 15, i3 = d >> 7;
        float s = 0.f;
        for (int p2 = 0; p2 < 8; ++p2)
            s += t2[(i2 * 8 + i1) * 8 + p2] * c2[p2 * 64 + i3 * 8 + p3];
        Msh[e] = s;
    }

    // N column for this o
    int n1 = o >> 7, nn = o & 127, n2 = nn >> 3, n3 = nn & 7;
    float v[8];
    for (int p4 = 0; p4 < 8; ++p4) {
        float s = 0.f;
        for (int p5 = 0; p5 < 8; ++p5)
            s += c4[p4 * 128 + n2 * 8 + p5] * c5[p5 * 8 + n3];
        v[p4] = s;
    }
    float ncol[8];
    for (int r3 = 0; r3 < 8; ++r3) {
        float s = 0.f;
        for (int p4 = 0; p4 < 8; ++p4)
            s += c3[r3 * 64 + n1 * 8 + p4] * v[p4];
        ncol[r3] = s;
    }
    __syncthreads();

    int d0 = tid * 4;
    f32x4 w = *(const f32x4*)&W[o * D_DIM + d0];
    bf16x4 res;
    for (int k = 0; k < 4; ++k) {
        float acc = 0.f;
        for (int r = 0; r < 8; ++r)
            acc += Msh[(d0 + k) * 8 + r] * ncol[r];
        res[k] = (bf16)(w[k] + ALPHA_F * acc);
    }
    *(bf16x4*)&Weff[o * D_DIM + d0] = res;
}

// ---- Kernel B: 16384x1024x1024 bf16 MFMA GEMM + bias, BK=64 -----------------
// LDS rows are 128 B = 8 x 16B chunks. Stored chunk = logical chunk ^ (row&7).
// Staging: lane l of issue j covers row w*32+j*8+(l>>3), stored chunk l&7,
// so it loads GLOBAL chunk (l&7)^(l>>3); LDS dst = uniform base + l*16 (legal).
// Reads: 16-lane quad-groups hit 8 distinct chunk slots -> 32 banks 2-way (free).
__global__ __launch_bounds__(256) void gemm_bb_kernel(
    const bf16* __restrict__ Xb,
    const bf16* __restrict__ Weff,
    const float* __restrict__ bias,
    float* __restrict__ Out)
{
    __shared__ __align__(16) bf16 As[BM][64];  // 16 KB
    __shared__ __align__(16) bf16 Bs[BN][64];  // 16 KB

    const int tid  = threadIdx.x;
    const int wave = tid >> 6, lane = tid & 63;
    const int mtile = blockIdx.x, ntile = blockIdx.y;
    const int wr = wave >> 1, wc = wave & 1;
    const int l15 = lane & 15, quad = lane >> 4;

    // Staging addresses (issue j adds j*8 rows)
    const int srow = wave * 32 + (lane >> 3);           // row for issue 0
    const int gchunk = (lane & 7) ^ (lane >> 3);        // swizzled global chunk
    const bf16* asrc = Xb   + (size_t)(mtile * BM + srow) * D_DIM + gchunk * 8;
    const bf16* bsrc = Weff + (size_t)(ntile * BN + srow) * D_DIM + gchunk * 8;
    char* abase = (char*)&As[0][0] + wave * 4096;
    char* bbase = (char*)&Bs[0][0] + wave * 4096;

    // Fragment read swizzle
    const int rsw = l15 & 7;

    f32x4 acc[4][4];
    for (int i = 0; i < 4; ++i)
        for (int j = 0; j < 4; ++j)
            for (int r = 0; r < 4; ++r) acc[i][j][r] = 0.f;

    for (int kt = 0; kt < D_DIM / 64; ++kt) {
        const int ko = kt * 64;
        for (int j = 0; j < 4; ++j) {
            __builtin_amdgcn_global_load_lds(GPTR(asrc + (size_t)j * 8 * D_DIM + ko),
                                             SPTR(abase + j * 1024), 16, 0, 0);
            __builtin_amdgcn_global_load_lds(GPTR(bsrc + (size_t)j * 8 * D_DIM + ko),
                                             SPTR(bbase + j * 1024), 16, 0, 0);
        }

        __syncthreads();

        for (int kk = 0; kk < 2; ++kk) {
            const int lc = kk * 4 + quad;            // logical chunk
            const int sc = (lc ^ rsw) * 8;           // stored chunk (elements)
            bf16x8 af[4], bfr[4];
            for (int i = 0; i < 4; ++i)
                af[i] = *(const bf16x8*)&As[wr * 64 + i * 16 + l15][sc];
            for (int j = 0; j < 4; ++j)
                bfr[j] = *(const bf16x8*)&Bs[wc * 64 + j * 16 + l15][sc];
            for (int i = 0; i < 4; ++i)
                for (int j = 0; j < 4; ++j)
                    acc[i][j] = __builtin_amdgcn_mfma_f32_16x16x32_bf16(
                        af[i], bfr[j], acc[i][j], 0, 0, 0);
        }

        __syncthreads();
    }

    // Epilogue: C/D layout col = lane&15, row = quad*4 + reg
    float bj[4];
    for (int j = 0; j < 4; ++j)
        bj[j] = bias[ntile * BN + wc * 64 + j * 16 + l15];
    for (int i = 0; i < 4; ++i) {
        int row0 = mtile * BM + wr * 64 + i * 16 + quad * 4;
        for (int r = 0; r < 4; ++r) {
            float* orow = Out + (size_t)(row0 + r) * D_DIM + ntile * BN + wc * 64 + l15;
            for (int j = 0; j < 4; ++j)
                orow[j * 16] = acc[i][j][r] + bj[j];
        }
    }
}

// ---- Fallback GEMM (fp32 A staged via VALU convert) — used if ws too small --
__global__ __launch_bounds__(256) void gemm_bias_kernel(
    const float* __restrict__ X,
    const bf16* __restrict__ Weff,
    const float* __restrict__ bias,
    float* __restrict__ Out)
{
    __shared__ __align__(16) bf16 As[BM][32];
    __shared__ __align__(16) bf16 Bs[BN][32];

    const int tid  = threadIdx.x;
    const int wave = tid >> 6, lane = tid & 63;
    const int mtile = blockIdx.x, ntile = blockIdx.y;
    const int wr = wave >> 1, wc = wave & 1;
    const int l15 = lane & 15, quad = lane >> 4;

    const int ar = tid >> 1, ah = tid & 1;
    const float* xsrc = X + (size_t)(mtile * BM + ar) * D_DIM + ah * 16;
    bf16* adst = &As[ar][ah * 16];

    const bf16* bsrc0 = Weff + (size_t)(ntile * BN + wave * 32 + (lane >> 2)) * D_DIM
                        + (lane & 3) * 8;
    const bf16* bsrc1 = bsrc0 + 16 * D_DIM;
    char* bbase = (char*)&Bs[0][0];
    void* bdst0 = bbase + wave * 2048;
    void* bdst1 = bbase + wave * 2048 + 1024;

    f32x4 acc[4][4];
    for (int i = 0; i < 4; ++i)
        for (int j = 0; j < 4; ++j)
            for (int r = 0; r < 4; ++r) acc[i][j][r] = 0.f;

    for (int kt = 0; kt < D_DIM / 32; ++kt) {
        __builtin_amdgcn_global_load_lds(GPTR(bsrc0 + kt * 32), SPTR(bdst0), 16, 0, 0);
        __builtin_amdgcn_global_load_lds(GPTR(bsrc1 + kt * 32), SPTR(bdst1), 16, 0, 0);

        const f32x4* xp = (const f32x4*)(xsrc + kt * 32);
        f32x4 f0 = xp[0], f1 = xp[1], f2 = xp[2], f3 = xp[3];
        bf16x8 p0, p1;
        p0[0] = (bf16)f0[0]; p0[1] = (bf16)f0[1]; p0[2] = (bf16)f0[2]; p0[3] = (bf16)f0[3];
        p0[4] = (bf16)f1[0]; p0[5] = (bf16)f1[1]; p0[6] = (bf16)f1[2]; p0[7] = (bf16)f1[3];
        p1[0] = (bf16)f2[0]; p1[1] = (bf16)f2[1]; p1[2] = (bf16)f2[2]; p1[3] = (bf16)f2[3];
        p1[4] = (bf16)f3[0]; p1[5] = (bf16)f3[1]; p1[6] = (bf16)f3[2]; p1[7] = (bf16)f3[3];
        *(bf16x8*)adst = p0;
        *(bf16x8*)(adst + 8) = p1;

        __syncthreads();

        bf16x8 af[4], bfr[4];
        for (int i = 0; i < 4; ++i)
            af[i] = *(const bf16x8*)&As[wr * 64 + i * 16 + l15][quad * 8];
        for (int j = 0; j < 4; ++j)
            bfr[j] = *(const bf16x8*)&Bs[wc * 64 + j * 16 + l15][quad * 8];
        for (int i = 0; i < 4; ++i)
            for (int j = 0; j < 4; ++j)
                acc[i][j] = __builtin_amdgcn_mfma_f32_16x16x32_bf16(
                    af[i], bfr[j], acc[i][j], 0, 0, 0);

        __syncthreads();
    }

    float bj[4];
    for (int j = 0; j < 4; ++j)
        bj[j] = bias[ntile * BN + wc * 64 + j * 16 + l15];
    for (int i = 0; i < 4; ++i) {
        int row0 = mtile * BM + wr * 64 + i * 16 + quad * 4;
        for (int r = 0; r < 4; ++r) {
            float* orow = Out + (size_t)(row0 + r) * D_DIM + ntile * BN + wc * 64 + l15;
            for (int j = 0; j < 4; ++j)
                orow[j * 16] = acc[i][j][r] + bj[j];
        }
    }
}

// Standalone Weff builder for fallback path
__global__ __launch_bounds__(256) void build_weff_fused_kernel(
    const float* __restrict__ W,
    const float* __restrict__ c0, const float* __restrict__ c1,
    const float* __restrict__ c2, const float* __restrict__ c3,
    const float* __restrict__ c4, const float* __restrict__ c5,
    bf16* __restrict__ Weff)
{
    __shared__ float t2[1024];
    __shared__ float Msh[8192];
    const int tid = threadIdx.x;
    const int o = blockIdx.x;

    for (int e = tid; e < 1024; e += 256) {
        int p2 = e & 7, i2i1 = e >> 3;
        int i1 = i2i1 & 7, i2 = i2i1 >> 3;
        float s = 0.f;
        for (int p1 = 0; p1 < 8; ++p1)
            s += c0[i1 * 8 + p1] * c1[p1 * 128 + i2 * 8 + p2];
        t2[e] = s;
    }
    __syncthreads();
    for (int e = tid; e < 8192; e += 256) {
        int p3 = e & 7, d = e >> 3;
        int i1 = d & 7, i2 = (d >> 3) & 15, i3 = d >> 7;
        float s = 0.f;
        for (int p2 = 0; p2 < 8; ++p2)
            s += t2[(i2 * 8 + i1) * 8 + p2] * c2[p2 * 64 + i3 * 8 + p3];
        Msh[e] = s;
    }
    int n1 = o >> 7, nn = o & 127, n2 = nn >> 3, n3 = nn & 7;
    float v[8];
    for (int p4 = 0; p4 < 8; ++p4) {
        float s = 0.f;
        for (int p5 = 0; p5 < 8; ++p5)
            s += c4[p4 * 128 + n2 * 8 + p5] * c5[p5 * 8 + n3];
        v[p4] = s;
    }
    float ncol[8];
    for (int r3 = 0; r3 < 8; ++r3) {
        float s = 0.f;
        for (int p4 = 0; p4 < 8; ++p4)
            s += c3[r3 * 64 + n1 * 8 + p4] * v[p4];
        ncol[r3] = s;
    }
    __syncthreads();

    int d0 = tid * 4;
    f32x4 w = *(const f32x4*)&W[o * D_DIM + d0];
    bf16x4 res;
    for (int k = 0; k < 4; ++k) {
        float acc = 0.f;
        for (int r = 0; r < 8; ++r)
            acc += Msh[(d0 + k) * 8 + r] * ncol[r];
        res[k] = (bf16)(w[k] + ALPHA_F * acc);
    }
    *(bf16x4*)&Weff[o * D_DIM + d0] = res;
}

extern "C" void kernel_launch(void* const* d_in, const int* in_sizes, int n_in,
                              void* d_out, int out_size, void* d_ws, size_t ws_size,
                              hipStream_t stream) {
    const float* x  = (const float*)d_in[0];
    const float* W  = (const float*)d_in[1];
    const float* b  = (const float*)d_in[2];
    const float* c0 = (const float*)d_in[3];
    const float* c1 = (const float*)d_in[4];
    const float* c2 = (const float*)d_in[5];
    const float* c3 = (const float*)d_in[6];
    const float* c4 = (const float*)d_in[7];
    const float* c5 = (const float*)d_in[8];
    float* out = (float*)d_out;

    // Workspace: Weff bf16 2MB @0 | Xb 32MB @4MB
    char* ws = (char*)d_ws;
    bf16* Weff = (bf16*)ws;
    bf16* Xb   = (bf16*)(ws + 4u * 1024u * 1024u);
    const size_t need = 4u * 1024u * 1024u + (size_t)BS_ROWS * D_DIM * 2u;

    dim3 grid(BS_ROWS / BM, D_DIM / BN);
    if (ws_size >= need) {
        prep_kernel<<<1024 + 8192, 256, 0, stream>>>(x, W, c0, c1, c2, c3, c4, c5,
                                                     Weff, Xb);
        gemm_bb_kernel<<<grid, 256, 0, stream>>>(Xb, Weff, b, out);
    } else {
        build_weff_fused_kernel<<<D_DIM, 256, 0, stream>>>(W, c0, c1, c2, c3, c4, c5, Weff);
        gemm_bias_kernel<<<grid, 256, 0, stream>>>(x, Weff, b, out);
    }
}